// Round 5
// baseline (355.821 us; speedup 1.0000x reference)
//
#include <hip/hip_runtime.h>
#include <stdint.h>

#define SEQ    2048
#define DMODEL 1024
#define NHEADS 16
#define HDIM   64
#define BATCH  4
#define MTOT   (BATCH*SEQ)

typedef __attribute__((ext_vector_type(8)))  short s16x8;
typedef __attribute__((ext_vector_type(4)))  short s16x4;
typedef __attribute__((ext_vector_type(4)))  float f32x4;
typedef __attribute__((ext_vector_type(16))) float f32x16;

// ---- workspace offsets (bytes) ----
#define OFF_SIN  ((size_t)0)          // 2048*32*4
#define OFF_COS  ((size_t)262144)
#define OFF_XHI  ((size_t)524288)     // 8192*1024*2
#define OFF_WQH  ((size_t)34078720)
#define OFF_WKH  ((size_t)38273024)
#define OFF_WVH  ((size_t)42467328)
#define OFF_WOH  ((size_t)46661632)
#define OFF_QR   ((size_t)50855936)   // [b,h,n,dh] bf16 (Q pre-scaled by 0.125*log2e)
#define OFF_KR   ((size_t)67633152)
#define OFF_VT   ((size_t)84410368)   // [b,h,dh,n] bf16 (transposed)
#define OFF_AHI  ((size_t)101187584)  // attn out [m,e] bf16

__device__ __forceinline__ uint16_t f2bf(float f){
  union{float f;uint32_t u;}v; v.f=f;
  uint32_t r=v.u+0x7fffu+((v.u>>16)&1u);
  return (uint16_t)(r>>16);
}
__device__ __forceinline__ float bf2f(uint16_t u){
  union{uint32_t u;float f;}v; v.u=((uint32_t)u)<<16; return v.f;
}

__device__ __forceinline__ void async16(void* lds, const void* g){
  __builtin_amdgcn_global_load_lds(
    (const __attribute__((address_space(1))) void*)g,
    (__attribute__((address_space(3))) void*)lds, 16, 0, 0);
}

__device__ __forceinline__ float fexp2(float x){
#if __has_builtin(__builtin_amdgcn_exp2f)
  return __builtin_amdgcn_exp2f(x);
#else
  float r; asm("v_exp_f32 %0, %1" : "=v"(r) : "v"(x)); return r;
#endif
}
__device__ __forceinline__ float frcp(float x){
#if __has_builtin(__builtin_amdgcn_rcpf)
  return __builtin_amdgcn_rcpf(x);
#else
  float r; asm("v_rcp_f32 %0, %1" : "=v"(r) : "v"(x)); return r;
#endif
}
// {o0,o1} = permlane32_swap(a,b): o0 = [a_lo|b_lo], o1 = [a_hi|b_hi]
__device__ __forceinline__ void plswap(unsigned a, unsigned b, unsigned &o0, unsigned &o1){
#if __has_builtin(__builtin_amdgcn_permlane32_swap)
  auto r = __builtin_amdgcn_permlane32_swap(a, b, false, false);
  o0 = (unsigned)r[0]; o1 = (unsigned)r[1];
#else
  unsigned ax = (unsigned)__shfl_xor((int)a, 32, 64);
  unsigned bx = (unsigned)__shfl_xor((int)b, 32, 64);
  bool hi = (threadIdx.x & 32) != 0;
  o0 = hi ? bx : a;
  o1 = hi ? b  : ax;
#endif
}

// ---------------- prep kernels ----------------
__global__ __launch_bounds__(256) void rope_tables_k(float* __restrict__ st, float* __restrict__ ct){
  int i = blockIdx.x*256 + threadIdx.x;
  if (i >= SEQ*32) return;
  int n = i>>5, j = i&31;
  double freq = pow(10000.0, -(double)j/32.0);
  double ang = (double)n*freq;
  st[i] = (float)sin(ang);
  ct[i] = (float)cos(ang);
}

__global__ __launch_bounds__(256) void cvt_k(const float* __restrict__ src,
                                             uint16_t* __restrict__ hi, int n4){
  int i = blockIdx.x*256 + threadIdx.x;
  if (i>=n4) return;
  f32x4 v = *(const f32x4*)(src + (size_t)i*4);
  s16x4 vh;
  #pragma unroll
  for(int r=0;r<4;r++) vh[r] = (short)f2bf(v[r]);
  *(s16x4*)(hi + (size_t)i*4) = vh;
}

// ---------------- GEMM core (128x128 tile, BK=32) ----------------
__device__ __forceinline__ void gemm_mainloop(
  const uint16_t* __restrict__ A, const uint16_t* __restrict__ B,
  int m0, int e0, uint16_t* lA, uint16_t* lB, f32x4 acc[4][4])
{
  const int t = threadIdx.x;
  const int lane = t & 63;
  const int wr = t>>7, wc = (t>>6)&1;
  const int lq = lane&15, lg = lane>>4;
  const int rowA = wr*64 + lq;
  const int rowB = wc*64 + lq;
  const int kb = lg*8;
  for(int k0=0;k0<DMODEL;k0+=32){
    #pragma unroll
    for(int r=0;r<2;r++){
      int idx = r*256+t;
      int row = idx>>2; int ce = (idx&3)*8;
      async16(lA + idx*8, A + (size_t)(m0+row)*DMODEL + k0 + ce);
      async16(lB + idx*8, B + (size_t)(e0+row)*DMODEL + k0 + ce);
    }
    __syncthreads();
    s16x8 af[4], bfr[4];
    #pragma unroll
    for(int mi=0;mi<4;mi++) af[mi]  = *(const s16x8*)(lA + (rowA+mi*16)*32 + kb);
    #pragma unroll
    for(int ni=0;ni<4;ni++) bfr[ni] = *(const s16x8*)(lB + (rowB+ni*16)*32 + kb);
    #pragma unroll
    for(int mi=0;mi<4;mi++){
      #pragma unroll
      for(int ni=0;ni<4;ni++)
        acc[mi][ni] = __builtin_amdgcn_mfma_f32_16x16x32_bf16(af[mi], bfr[ni], acc[mi][ni],0,0,0);
    }
    __syncthreads();
  }
}

// ---------------- QKV projection + RoPE epilogue ----------------
__global__ __launch_bounds__(256) void gemm_qkv_k(
  const uint16_t* __restrict__ Xh,
  const uint16_t* __restrict__ WqH, const uint16_t* __restrict__ WkH, const uint16_t* __restrict__ WvH,
  const float* __restrict__ st, const float* __restrict__ ct,
  uint16_t* __restrict__ Qr, uint16_t* __restrict__ Kr, uint16_t* __restrict__ Vt)
{
  __shared__ uint16_t lA[128*32], lB[128*32];
  int m0 = blockIdx.x*128;
  int cti = blockIdx.y;
  int seg = cti>>3;                 // 0=Q 1=K 2=V
  int e0 = (cti&7)*128;
  const uint16_t* W = seg==0? WqH : (seg==1? WkH : WvH);
  f32x4 acc[4][4];
  #pragma unroll
  for(int i=0;i<4;i++){
    #pragma unroll
    for(int j=0;j<4;j++) acc[i][j] = (f32x4){0.f,0.f,0.f,0.f};
  }
  gemm_mainloop(Xh, W, m0, e0, lA, lB, acc);

  int t=threadIdx.x, lane=t&63, lq=lane&15, lg=lane>>4;
  int wr=t>>7, wc=(t>>6)&1;
  int eb = e0 + wc*64;
  int h = eb>>6;                    // wave col-span is head-aligned (64 wide)
  int rbase = m0 + wr*64 + lg*4;
  if (seg<2){
    uint16_t* O = seg==0? Qr:Kr;
    float qs = seg==0 ? 0.18033688011112042f : 1.0f;  // 0.125*log2(e) folded into Q
    #pragma unroll
    for(int mi=0;mi<4;mi++){
      #pragma unroll
      for(int ni=0;ni<2;ni++){
        int j = ni*16+lq;           // 0..31, pairs with j+32 in frag ni+2
        #pragma unroll
        for(int r=0;r<4;r++){
          int m = rbase + mi*16 + r;
          int b = m>>11, n = m&2047;
          float sv = st[n*32+j], cv = ct[n*32+j];
          float x1 = acc[mi][ni][r], x2 = acc[mi][ni+2][r];
          size_t base = ((size_t)((b*NHEADS+h)*SEQ + n))*HDIM;
          O[base + j]      = f2bf((x1*cv - x2*sv)*qs);
          O[base + j + 32] = f2bf((x1*sv + x2*cv)*qs);
        }
      }
    }
  } else {
    #pragma unroll
    for(int mi=0;mi<4;mi++){
      #pragma unroll
      for(int ni=0;ni<4;ni++){
        int dh = ni*16+lq;
        int m = rbase + mi*16;
        int b = m>>11, n = m&2047;  // 4 consecutive n over regs
        s16x4 v;
        #pragma unroll
        for(int r=0;r<4;r++) v[r] = (short)f2bf(acc[mi][ni][r]);
        *(s16x4*)(Vt + ((size_t)((b*NHEADS+h)*HDIM + dh))*SEQ + n) = v;
      }
    }
  }
}

// ---------------- flash attention: no-LDS, direct-global K/V, fixed-max softmax ----------------
__global__ __launch_bounds__(256, 4) void attn_k(
  const uint16_t* __restrict__ Qr, const uint16_t* __restrict__ Kr, const uint16_t* __restrict__ Vt,
  uint16_t* __restrict__ Ah)
{
  int bid = blockIdx.x;
  int w = (bid & 7)*128 + (bid >> 3);   // XCD swizzle: 16 q-tiles of one bh per XCD
  int bh = w >> 4, qt = w & 15;
  int tid = threadIdx.x;
  int wid = tid >> 6, lane = tid & 63;
  int l31 = lane & 31, hi = lane >> 5;
  int q0 = qt*128 + wid*32;

  const uint16_t* Qb = Qr + (size_t)bh*SEQ*HDIM;
  // per-lane base pointers (byte arithmetic)
  const char* kbase = (const char*)(Kr + (size_t)bh*SEQ*HDIM) + (size_t)l31*128 + hi*16;
  const char* vbase = (const char*)(Vt + (size_t)bh*HDIM*SEQ) + (size_t)l31*4096 + hi*16;

  // Q B-frags: col=q=l31, k=d=16*sp+8*hi+j  (Q pre-scaled by 0.125*log2e)
  s16x8 qf[4];
  #pragma unroll
  for (int sp=0; sp<4; ++sp)
    qf[sp] = *(const s16x8*)(Qb + (size_t)(q0 + l31)*HDIM + sp*16 + hi*8);

  // ones B-frag (bf16 1.0) for the L row-sum MFMA
  s16x8 ones;
  #pragma unroll
  for (int j=0;j<8;j++) ones[j] = (short)0x3F80;

  f32x16 oa[2], lacc;
  #pragma unroll
  for (int r=0;r<16;r++){ oa[0][r]=0.f; oa[1][r]=0.f; lacc[r]=0.f; }

  // K frag (kv-step t): row k = t*32 + l31, dh chunk sp*32 + hi*16 bytes
  // V frag (db,s): row dh = db*32 + l31, kv bytes t*64 + s*32 + hi*16
  s16x8 kf[4], vf[4];
  #pragma unroll
  for (int sp=0; sp<4; ++sp) kf[sp] = *(const s16x8*)(kbase + sp*32);
  #pragma unroll
  for (int db=0; db<2; ++db)
    #pragma unroll
    for (int s=0; s<2; ++s)
      vf[db*2+s] = *(const s16x8*)(vbase + db*32*4096 + s*32);

  const int NT = SEQ/32;
  for (int t=0; t<NT; ++t){
    f32x16 sacc;
    #pragma unroll
    for (int r=0;r<16;r++) sacc[r]=0.f;
    __builtin_amdgcn_s_setprio(1);
    #pragma unroll
    for (int sp=0; sp<4; ++sp)
      sacc = __builtin_amdgcn_mfma_f32_32x32x16_bf16(kf[sp], qf[sp], sacc, 0,0,0);
    __builtin_amdgcn_s_setprio(0);
    // prefetch next K (regs renamed; latency hidden under softmax)
    if (t+1 < NT){
      const char* kp = kbase + (size_t)(t+1)*4096;
      #pragma unroll
      for (int sp=0; sp<4; ++sp) kf[sp] = *(const s16x8*)(kp + sp*32);
    }
    // S^T[k][q]: k = (r&3)+8*(r>>2)+4*hi, q = l31.
    // Fixed-max softmax: p = exp2(sacc - 16); normalization by L makes the shift exact.
    float p[16];
    #pragma unroll
    for (int r=0;r<16;r++) p[r] = fexp2(sacc[r] - 16.0f);
    uint32_t pw[8];
    #pragma unroll
    for (int j=0;j<8;j++)
      asm("v_cvt_pk_bf16_f32 %0, %1, %2" : "=v"(pw[j]) : "v"(p[2*j]), "v"(p[2*j+1]));
    // P^T acc-layout -> PV A-frag (row=q, k) via 4 permlane32_swap
    unsigned w0,w1,w2,w3, x0,x1,x2,x3;
    plswap(pw[0], pw[2], w0, w2);
    plswap(pw[1], pw[3], w1, w3);
    plswap(pw[4], pw[6], x0, x2);
    plswap(pw[5], pw[7], x1, x3);
    union { uint32_t wd[4]; s16x8 v; } pa0, pa1;
    pa0.wd[0]=w0; pa0.wd[1]=w1; pa0.wd[2]=w2; pa0.wd[3]=w3;
    pa1.wd[0]=x0; pa1.wd[1]=x1; pa1.wd[2]=x2; pa1.wd[3]=x3;
    __builtin_amdgcn_s_setprio(1);
    #pragma unroll
    for (int db=0; db<2; ++db){
      oa[db] = __builtin_amdgcn_mfma_f32_32x32x16_bf16(pa0.v, vf[db*2+0], oa[db], 0,0,0);
      oa[db] = __builtin_amdgcn_mfma_f32_32x32x16_bf16(pa1.v, vf[db*2+1], oa[db], 0,0,0);
    }
    // L row-sum on the matrix pipe: lacc[q] += sum_k P[q][k]
    lacc = __builtin_amdgcn_mfma_f32_32x32x16_bf16(pa0.v, ones, lacc, 0,0,0);
    lacc = __builtin_amdgcn_mfma_f32_32x32x16_bf16(pa1.v, ones, lacc, 0,0,0);
    __builtin_amdgcn_s_setprio(0);
    // prefetch next V (latency hidden under next QK + softmax)
    if (t+1 < NT){
      const char* vp = vbase + (size_t)(t+1)*64;
      #pragma unroll
      for (int db=0; db<2; ++db)
        #pragma unroll
        for (int s=0; s<2; ++s)
          vf[db*2+s] = *(const s16x8*)(vp + db*32*4096 + s*32);
    }
  }

  // epilogue: L already in acc layout; normalize and write bf16
  int b = bh >> 4, h = bh & 15;
  #pragma unroll
  for (int r=0;r<16;r++){
    int q = (r&3) + 8*(r>>2) + 4*hi;
    float inv = frcp(lacc[r]);
    size_t mrow = ((size_t)(b*SEQ + q0 + q))*DMODEL + (size_t)h*HDIM + l31;
    #pragma unroll
    for (int db=0; db<2; ++db)
      Ah[mrow + db*32] = f2bf(oa[db][r]*inv);
  }
}

// ---------------- output projection ----------------
__global__ __launch_bounds__(256) void gemm_out_k(
  const uint16_t* __restrict__ Ahp, const uint16_t* __restrict__ WoH, float* __restrict__ C)
{
  __shared__ uint16_t lA[128*32], lB[128*32];
  int m0 = blockIdx.x*128;
  int e0 = blockIdx.y*128;
  f32x4 acc[4][4];
  #pragma unroll
  for(int i=0;i<4;i++){
    #pragma unroll
    for(int j=0;j<4;j++) acc[i][j] = (f32x4){0.f,0.f,0.f,0.f};
  }
  gemm_mainloop(Ahp, WoH, m0, e0, lA, lB, acc);
  int t=threadIdx.x, lane=t&63, lq=lane&15, lg=lane>>4;
  int wr=t>>7, wc=(t>>6)&1;
  int rbase = m0 + wr*64 + lg*4;
  int cb = e0 + wc*64;
  #pragma unroll
  for(int mi=0;mi<4;mi++){
    #pragma unroll
    for(int ni=0;ni<4;ni++){
      #pragma unroll
      for(int r=0;r<4;r++)
        C[(size_t)(rbase+mi*16+r)*DMODEL + cb + ni*16 + lq] = acc[mi][ni][r];
    }
  }
}

extern "C" void kernel_launch(void* const* d_in, const int* in_sizes, int n_in,
                              void* d_out, int out_size, void* d_ws, size_t ws_size,
                              hipStream_t stream) {
  const float* x  = (const float*)d_in[0];
  const float* Wq = (const float*)d_in[1];
  const float* Wk = (const float*)d_in[2];
  const float* Wv = (const float*)d_in[3];
  const float* Wo = (const float*)d_in[4];
  float* out = (float*)d_out;
  char* ws = (char*)d_ws;

  float* sin_t = (float*)(ws + OFF_SIN);
  float* cos_t = (float*)(ws + OFF_COS);
  uint16_t* xhi = (uint16_t*)(ws + OFF_XHI);
  uint16_t* wqh = (uint16_t*)(ws + OFF_WQH);
  uint16_t* wkh = (uint16_t*)(ws + OFF_WKH);
  uint16_t* wvh = (uint16_t*)(ws + OFF_WVH);
  uint16_t* woh = (uint16_t*)(ws + OFF_WOH);
  uint16_t* Qr  = (uint16_t*)(ws + OFF_QR);
  uint16_t* Kr  = (uint16_t*)(ws + OFF_KR);
  uint16_t* Vt  = (uint16_t*)(ws + OFF_VT);
  uint16_t* ahi = (uint16_t*)(ws + OFF_AHI);

  rope_tables_k<<<dim3(256),dim3(256),0,stream>>>(sin_t, cos_t);
  cvt_k<<<dim3(8192),dim3(256),0,stream>>>(x,  xhi, (MTOT*DMODEL)/4);
  cvt_k<<<dim3(1024),dim3(256),0,stream>>>(Wq, wqh, (DMODEL*DMODEL)/4);
  cvt_k<<<dim3(1024),dim3(256),0,stream>>>(Wk, wkh, (DMODEL*DMODEL)/4);
  cvt_k<<<dim3(1024),dim3(256),0,stream>>>(Wv, wvh, (DMODEL*DMODEL)/4);
  cvt_k<<<dim3(1024),dim3(256),0,stream>>>(Wo, woh, (DMODEL*DMODEL)/4);

  gemm_qkv_k<<<dim3(MTOT/128, 24),dim3(256),0,stream>>>(xhi, wqh, wkh, wvh,
                                                        sin_t, cos_t, Qr, Kr, Vt);
  attn_k<<<dim3(BATCH*NHEADS*(SEQ/128)),dim3(256),0,stream>>>(Qr, Kr, Vt, ahi);
  gemm_out_k<<<dim3(MTOT/128, 8),dim3(256),0,stream>>>(ahi, woh, out);
}

// Round 6
// 226.528 us; speedup vs baseline: 1.5708x; 1.5708x over previous
//
#include <hip/hip_runtime.h>
#include <stdint.h>

#define SEQ    2048
#define DMODEL 1024
#define NHEADS 16
#define HDIM   64
#define BATCH  4
#define MTOT   (BATCH*SEQ)

typedef __attribute__((ext_vector_type(8)))  short s16x8;
typedef __attribute__((ext_vector_type(4)))  short s16x4;
typedef __attribute__((ext_vector_type(4)))  float f32x4;
typedef __attribute__((ext_vector_type(16))) float f32x16;

// ---- workspace offsets (bytes) ----
#define OFF_SIN  ((size_t)0)          // 2048*32*4
#define OFF_COS  ((size_t)262144)
#define OFF_XHI  ((size_t)524288)     // 8192*1024*2
#define OFF_WQH  ((size_t)34078720)
#define OFF_WKH  ((size_t)38273024)
#define OFF_WVH  ((size_t)42467328)
#define OFF_WOH  ((size_t)46661632)
#define OFF_QR   ((size_t)50855936)   // [b,h,n,dh] bf16 (Q pre-scaled by 0.125*log2e)
#define OFF_KR   ((size_t)67633152)
#define OFF_VT   ((size_t)84410368)   // [b,h,dh,n] bf16 (transposed)
#define OFF_AHI  ((size_t)101187584)  // attn out [m,e] bf16

#define QSCALE 0.18033688011112042f

__device__ __forceinline__ uint16_t f2bf(float f){
  union{float f;uint32_t u;}v; v.f=f;
  uint32_t r=v.u+0x7fffu+((v.u>>16)&1u);
  return (uint16_t)(r>>16);
}
__device__ __forceinline__ float bf2f(uint16_t u){
  union{uint32_t u;float f;}v; v.u=((uint32_t)u)<<16; return v.f;
}

__device__ __forceinline__ void async16(void* lds, const void* g){
  __builtin_amdgcn_global_load_lds(
    (const __attribute__((address_space(1))) void*)g,
    (__attribute__((address_space(3))) void*)lds, 16, 0, 0);
}

__device__ __forceinline__ float fexp2(float x){
#if __has_builtin(__builtin_amdgcn_exp2f)
  return __builtin_amdgcn_exp2f(x);
#else
  float r; asm("v_exp_f32 %0, %1" : "=v"(r) : "v"(x)); return r;
#endif
}
__device__ __forceinline__ float frcp(float x){
#if __has_builtin(__builtin_amdgcn_rcpf)
  return __builtin_amdgcn_rcpf(x);
#else
  float r; asm("v_rcp_f32 %0, %1" : "=v"(r) : "v"(x)); return r;
#endif
}
// {o0,o1} = permlane32_swap(a,b)
__device__ __forceinline__ void plswap(unsigned a, unsigned b, unsigned &o0, unsigned &o1){
#if __has_builtin(__builtin_amdgcn_permlane32_swap)
  auto r = __builtin_amdgcn_permlane32_swap(a, b, false, false);
  o0 = (unsigned)r[0]; o1 = (unsigned)r[1];
#else
  unsigned ax = (unsigned)__shfl_xor((int)a, 32, 64);
  unsigned bx = (unsigned)__shfl_xor((int)b, 32, 64);
  bool hi = (threadIdx.x & 32) != 0;
  o0 = hi ? bx : a;
  o1 = hi ? b  : ax;
#endif
}

// ---------------- prep kernels ----------------
__global__ __launch_bounds__(256) void rope_tables_k(float* __restrict__ st, float* __restrict__ ct){
  int i = blockIdx.x*256 + threadIdx.x;
  if (i >= SEQ*32) return;
  int n = i>>5, j = i&31;
  double freq = pow(10000.0, -(double)j/32.0);
  double ang = (double)n*freq;
  st[i] = (float)sin(ang);
  ct[i] = (float)cos(ang);
}

__global__ __launch_bounds__(256) void cvt_k(const float* __restrict__ src,
                                             uint16_t* __restrict__ hi, int n4){
  int i = blockIdx.x*256 + threadIdx.x;
  if (i>=n4) return;
  f32x4 v = *(const f32x4*)(src + (size_t)i*4);
  s16x4 vh;
  #pragma unroll
  for(int r=0;r<4;r++) vh[r] = (short)f2bf(v[r]);
  *(s16x4*)(hi + (size_t)i*4) = vh;
}

__global__ __launch_bounds__(256) void cvtw_k(const float* __restrict__ s0, const float* __restrict__ s1,
                                              const float* __restrict__ s2, const float* __restrict__ s3,
                                              uint16_t* __restrict__ d0, uint16_t* __restrict__ d1,
                                              uint16_t* __restrict__ d2, uint16_t* __restrict__ d3){
  int i = blockIdx.x*256 + threadIdx.x;   // i < 262144
  int y = blockIdx.y;
  const float* s = y==0? s0 : y==1? s1 : y==2? s2 : s3;
  uint16_t*    d = y==0? d0 : y==1? d1 : y==2? d2 : d3;
  f32x4 v = *(const f32x4*)(s + (size_t)i*4);
  s16x4 vh;
  #pragma unroll
  for(int r=0;r<4;r++) vh[r] = (short)f2bf(v[r]);
  *(s16x4*)(d + (size_t)i*4) = vh;
}

// ---------------- QKV projection: 256x256 tile, BK=32, 4-phase pipelined ----------------
// 512 threads = 8 waves (2 wm x 4 wn), per-wave output 128x64.
// LDS: 3 A-buffers + 2 B-buffers (16KB each, 80KB total), circular over K-tiles.
// Pair-packed swizzle: LDS 128B line = 2 matrix rows; slot s=(4*(m&1)+c)^((m>>1)&7).
__global__ __launch_bounds__(512) void gemm_qkv_k(
  const uint16_t* __restrict__ Xh,
  const uint16_t* __restrict__ WqH, const uint16_t* __restrict__ WkH, const uint16_t* __restrict__ WvH,
  const float* __restrict__ st, const float* __restrict__ ct,
  uint16_t* __restrict__ Qr, uint16_t* __restrict__ Kr, uint16_t* __restrict__ Vt)
{
  __shared__ uint16_t ldsA[3*256*32];   // 3 x 16KB
  __shared__ uint16_t ldsB[2*256*32];   // 2 x 16KB

  const int tid = threadIdx.x;
  const int lane = tid & 63, wid = tid >> 6;
  const int lq = lane & 15, lg = lane >> 4;
  const int wm = wid >> 2, wn = wid & 3;
  const int m0 = blockIdx.x * 256;
  const int by = blockIdx.y;
  const int seg = by >> 2;               // 0=Q 1=K 2=V
  const int e0w = (by & 3) * 256;        // col offset within the 1024-wide W
  const uint16_t* W = seg==0? WqH : (seg==1? WkH : WvH);

  // per-lane LDS read byte-offsets (within a 16KB tile buffer)
  int aoff[8], boff[4];
  #pragma unroll
  for (int mi=0; mi<8; ++mi){
    int m = wm*128 + mi*16 + lq;
    int g = m >> 1;
    int s = (4*(m&1) + lg) ^ (g & 7);
    aoff[mi] = g*128 + s*16;
  }
  #pragma unroll
  for (int ni=0; ni<4; ++ni){
    int e = wn*64 + ni*16 + lq;
    int g = e >> 1;
    int s = (4*(e&1) + lg) ^ (g & 7);
    boff[ni] = g*128 + s*16;
  }

  // per-thread stage source mapping (inverse of the pair-packed swizzle)
  const int sg = tid >> 3, ss = tid & 7;
  const int mih = 2*sg + ((ss ^ (sg&7)) >> 2);   // matrix row within 128-row half
  const int cch = (ss ^ (sg&7)) & 3;             // 16B chunk within the 64B k-row
  const char* Asrc = (const char*)Xh;
  const char* Bsrc = (const char*)W;
  const size_t a_off0 = (size_t)(m0  + mih) * 2048 + (size_t)cch*16;
  const size_t b_off0 = (size_t)(e0w + mih) * 2048 + (size_t)cch*16;
  char* dA = (char*)ldsA;
  char* dB = (char*)ldsB;

  auto STG_A = [&](int buf, int kt){
    char* d = dA + buf*16384 + (tid<<4);
    const char* s = Asrc + a_off0 + (size_t)kt*64;
    async16(d,        s);              // rows 0..127
    async16(d + 8192, s + 262144);     // rows 128..255 (128*2048B)
  };
  auto STG_B = [&](int buf, int kt){
    char* d = dB + buf*16384 + (tid<<4);
    const char* s = Bsrc + b_off0 + (size_t)kt*64;
    async16(d,        s);
    async16(d + 8192, s + 262144);
  };

  f32x4 acc[8][4];
  #pragma unroll
  for (int i=0;i<8;i++)
    #pragma unroll
    for (int j=0;j<4;j++) acc[i][j] = (f32x4){0.f,0.f,0.f,0.f};
  s16x8 bfr[4];

  // prologue: stage tiles 0,1
  STG_A(0, 0); STG_B(0, 0); STG_A(1, 1); STG_B(1, 1);
  asm volatile("s_waitcnt vmcnt(4)" ::: "memory");
  asm volatile("s_barrier" ::: "memory");

  int eA = 0, oA = 1;
  for (int it=0; it<16; ++it){
    const char* aE = dA + eA*16384;
    const char* aO = dA + oA*16384;
    const char* bE = dB;
    const char* bO = dB + 16384;
    int sE = eA+2; if (sE>=3) sE-=3;
    int sO = oA+2; if (sO>=3) sO-=3;
    const bool STG = (it < 15);
    const int E = 2*it;

    // ---- phase 1: tile E, m-frags 0..3 ----
    {
      s16x8 af[4];
      #pragma unroll
      for (int j=0;j<4;++j) af[j] = *(const s16x8*)(aE + aoff[j]);
      #pragma unroll
      for (int n=0;n<4;++n) bfr[n] = *(const s16x8*)(bE + boff[n]);
      if (STG) STG_A(sE, E+2);
      __builtin_amdgcn_s_setprio(1);
      #pragma unroll
      for (int j=0;j<4;++j)
        #pragma unroll
        for (int n=0;n<4;++n)
          acc[j][n] = __builtin_amdgcn_mfma_f32_16x16x32_bf16(af[j], bfr[n], acc[j][n],0,0,0);
      __builtin_amdgcn_s_setprio(0);
      asm volatile("s_barrier" ::: "memory");
    }
    // ---- phase 2: tile E, m-frags 4..7 ----
    {
      s16x8 af[4];
      #pragma unroll
      for (int j=0;j<4;++j) af[j] = *(const s16x8*)(aE + aoff[4+j]);
      if (STG) STG_B(0, E+2);
      __builtin_amdgcn_s_setprio(1);
      #pragma unroll
      for (int j=0;j<4;++j)
        #pragma unroll
        for (int n=0;n<4;++n)
          acc[4+j][n] = __builtin_amdgcn_mfma_f32_16x16x32_bf16(af[j], bfr[n], acc[4+j][n],0,0,0);
      __builtin_amdgcn_s_setprio(0);
      if (STG) asm volatile("s_waitcnt vmcnt(4)" ::: "memory");
      else     asm volatile("s_waitcnt vmcnt(0)" ::: "memory");
      asm volatile("s_barrier" ::: "memory");
    }
    // ---- phase 3: tile O=E+1, m-frags 0..3 ----
    {
      s16x8 af[4];
      #pragma unroll
      for (int j=0;j<4;++j) af[j] = *(const s16x8*)(aO + aoff[j]);
      #pragma unroll
      for (int n=0;n<4;++n) bfr[n] = *(const s16x8*)(bO + boff[n]);
      if (STG) STG_A(sO, E+3);
      __builtin_amdgcn_s_setprio(1);
      #pragma unroll
      for (int j=0;j<4;++j)
        #pragma unroll
        for (int n=0;n<4;++n)
          acc[j][n] = __builtin_amdgcn_mfma_f32_16x16x32_bf16(af[j], bfr[n], acc[j][n],0,0,0);
      __builtin_amdgcn_s_setprio(0);
      asm volatile("s_barrier" ::: "memory");
    }
    // ---- phase 4: tile O, m-frags 4..7 ----
    {
      s16x8 af[4];
      #pragma unroll
      for (int j=0;j<4;++j) af[j] = *(const s16x8*)(aO + aoff[4+j]);
      if (STG) STG_B(1, E+3);
      __builtin_amdgcn_s_setprio(1);
      #pragma unroll
      for (int j=0;j<4;++j)
        #pragma unroll
        for (int n=0;n<4;++n)
          acc[4+j][n] = __builtin_amdgcn_mfma_f32_16x16x32_bf16(af[j], bfr[n], acc[4+j][n],0,0,0);
      __builtin_amdgcn_s_setprio(0);
      if (STG){
        asm volatile("s_waitcnt vmcnt(4)" ::: "memory");
        asm volatile("s_barrier" ::: "memory");
      }
    }
    eA += 2; if (eA>=3) eA-=3;
    oA += 2; if (oA>=3) oA-=3;
  }

  // ---- epilogue ----
  const int rbase = m0 + wm*128 + lg*4;
  const int hh = (e0w + wn*64) >> 6;     // head 0..15
  if (seg < 2){
    uint16_t* Op = seg==0? Qr : Kr;
    float qs = seg==0? QSCALE : 1.0f;
    #pragma unroll
    for (int mi=0; mi<8; ++mi){
      #pragma unroll
      for (int ni=0; ni<2; ++ni){
        int j = ni*16 + lq;              // pairs with j+32 in frag ni+2
        #pragma unroll
        for (int r=0; r<4; ++r){
          int m = rbase + mi*16 + r;
          int b = m>>11, n = m&2047;
          float sv = st[n*32+j], cv = ct[n*32+j];
          float x1 = acc[mi][ni][r], x2 = acc[mi][ni+2][r];
          size_t base = ((size_t)((b*NHEADS+hh)*SEQ + n))*HDIM;
          Op[base + j]      = f2bf((x1*cv - x2*sv)*qs);
          Op[base + j + 32] = f2bf((x1*sv + x2*cv)*qs);
        }
      }
    }
  } else {
    #pragma unroll
    for (int mi=0; mi<8; ++mi){
      #pragma unroll
      for (int ni=0; ni<4; ++ni){
        int dh = ni*16+lq;
        int m = rbase + mi*16;
        int b = m>>11, n = m&2047;
        s16x4 v;
        #pragma unroll
        for (int r=0;r<4;r++) v[r] = (short)f2bf(acc[mi][ni][r]);
        *(s16x4*)(Vt + ((size_t)((b*NHEADS+hh)*HDIM + dh))*SEQ + n) = v;
      }
    }
  }
}

// ---------------- GEMM core (128x128 tile, BK=32) — used by gemm_out ----------------
__device__ __forceinline__ void gemm_mainloop(
  const uint16_t* __restrict__ A, const uint16_t* __restrict__ B,
  int m0, int e0, uint16_t* lA, uint16_t* lB, f32x4 acc[4][4])
{
  const int t = threadIdx.x;
  const int lane = t & 63;
  const int wr = t>>7, wc = (t>>6)&1;
  const int lq = lane&15, lg = lane>>4;
  const int rowA = wr*64 + lq;
  const int rowB = wc*64 + lq;
  const int kb = lg*8;
  for(int k0=0;k0<DMODEL;k0+=32){
    #pragma unroll
    for(int r=0;r<2;r++){
      int idx = r*256+t;
      int row = idx>>2; int ce = (idx&3)*8;
      async16(lA + idx*8, A + (size_t)(m0+row)*DMODEL + k0 + ce);
      async16(lB + idx*8, B + (size_t)(e0+row)*DMODEL + k0 + ce);
    }
    __syncthreads();
    s16x8 af[4], bfr[4];
    #pragma unroll
    for(int mi=0;mi<4;mi++) af[mi]  = *(const s16x8*)(lA + (rowA+mi*16)*32 + kb);
    #pragma unroll
    for(int ni=0;ni<4;ni++) bfr[ni] = *(const s16x8*)(lB + (rowB+ni*16)*32 + kb);
    #pragma unroll
    for(int mi=0;mi<4;mi++){
      #pragma unroll
      for(int ni=0;ni<4;ni++)
        acc[mi][ni] = __builtin_amdgcn_mfma_f32_16x16x32_bf16(af[mi], bfr[ni], acc[mi][ni],0,0,0);
    }
    __syncthreads();
  }
}

// ---------------- flash attention (R4 known-good): 32x32 MFMA, LDS-staged K/V ----------------
__global__ __launch_bounds__(256) void attn_k(
  const uint16_t* __restrict__ Qr, const uint16_t* __restrict__ Kr, const uint16_t* __restrict__ Vt,
  uint16_t* __restrict__ Ah)
{
  __shared__ uint16_t ldsK[2][64*64];
  __shared__ uint16_t ldsV[2][64*64];

  int bid = blockIdx.x;
  int w = (bid & 7)*128 + (bid >> 3);   // XCD swizzle
  int bh = w >> 4, qt = w & 15;
  int tid = threadIdx.x;
  int wid = tid >> 6, lane = tid & 63;
  int l31 = lane & 31, hi = lane >> 5;
  int q0 = qt*128 + wid*32;

  const uint16_t* Qb = Qr + (size_t)bh*SEQ*HDIM;
  const uint16_t* Kb = Kr + (size_t)bh*SEQ*HDIM;
  const uint16_t* Vb = Vt + (size_t)bh*HDIM*SEQ;

  s16x8 qf[4];
  #pragma unroll
  for (int sp=0; sp<4; ++sp)
    qf[sp] = *(const s16x8*)(Qb + (size_t)(q0 + l31)*HDIM + sp*16 + hi*8);

  s16x8 ones;
  #pragma unroll
  for (int j=0;j<8;j++) ones[j] = (short)0x3F80;

  f32x16 oa[2], lacc;
  #pragma unroll
  for (int r=0;r<16;r++){ oa[0][r]=0.f; oa[1][r]=0.f; lacc[r]=0.f; }

  auto STAGE = [&](int buf, int t){
    const char* Ks = (const char*)(Kb + (size_t)t*64*HDIM);
    char* dK = (char*)&ldsK[buf][0];
    char* dV = (char*)&ldsV[buf][0];
    #pragma unroll
    for (int r=0; r<2; ++r){
      int ci = r*256 + tid;
      int sc = ci ^ ((ci>>3)&7);
      async16(dK + ci*16, Ks + sc*16);
    }
    #pragma unroll
    for (int r=0; r<2; ++r){
      int ci = r*256 + tid;
      int row = ci>>3;
      int sc = (ci&7) ^ (row&7);
      async16(dV + ci*16, (const char*)Vb + ((size_t)row*SEQ + (size_t)t*64)*2 + sc*16);
    }
  };

  STAGE(0, 0);
  asm volatile("s_waitcnt vmcnt(0)" ::: "memory");
  __syncthreads();

  const int NT = SEQ/64;
  for (int t=0; t<NT; ++t){
    int cur = t & 1;
    if (t+1 < NT) STAGE(cur^1, t+1);
    const char* bK = (const char*)&ldsK[cur][0];
    const char* bV = (const char*)&ldsV[cur][0];
    #pragma unroll
    for (int sub=0; sub<2; ++sub){
      int krow = sub*32 + l31;
      s16x8 kf[4];
      #pragma unroll
      for (int sp=0; sp<4; ++sp){
        int cc = (2*sp + hi) ^ (l31 & 7);
        kf[sp] = *(const s16x8*)(bK + krow*128 + cc*16);
      }
      f32x16 sacc;
      #pragma unroll
      for (int r=0;r<16;r++) sacc[r]=0.f;
      __builtin_amdgcn_s_setprio(1);
      #pragma unroll
      for (int sp=0; sp<4; ++sp)
        sacc = __builtin_amdgcn_mfma_f32_32x32x16_bf16(kf[sp], qf[sp], sacc, 0,0,0);
      __builtin_amdgcn_s_setprio(0);
      float p[16];
      #pragma unroll
      for (int r=0;r<16;r++) p[r] = fexp2(sacc[r] - 16.0f);
      uint32_t pw[8];
      #pragma unroll
      for (int j=0;j<8;j++)
        asm("v_cvt_pk_bf16_f32 %0, %1, %2" : "=v"(pw[j]) : "v"(p[2*j]), "v"(p[2*j+1]));
      unsigned w0,w1,w2,w3, x0,x1,x2,x3;
      plswap(pw[0], pw[2], w0, w2);
      plswap(pw[1], pw[3], w1, w3);
      plswap(pw[4], pw[6], x0, x2);
      plswap(pw[5], pw[7], x1, x3);
      union { uint32_t wd[4]; s16x8 v; } pa0, pa1;
      pa0.wd[0]=w0; pa0.wd[1]=w1; pa0.wd[2]=w2; pa0.wd[3]=w3;
      pa1.wd[0]=x0; pa1.wd[1]=x1; pa1.wd[2]=x2; pa1.wd[3]=x3;
      __builtin_amdgcn_s_setprio(1);
      #pragma unroll
      for (int db=0; db<2; ++db){
        int vrow = db*32 + l31;
        #pragma unroll
        for (int s=0; s<2; ++s){
          int cc = (4*sub + 2*s + hi) ^ (l31 & 7);
          s16x8 vf = *(const s16x8*)(bV + vrow*128 + cc*16);
          oa[db] = __builtin_amdgcn_mfma_f32_32x32x16_bf16(s? pa1.v : pa0.v, vf, oa[db], 0,0,0);
        }
      }
      lacc = __builtin_amdgcn_mfma_f32_32x32x16_bf16(pa0.v, ones, lacc, 0,0,0);
      lacc = __builtin_amdgcn_mfma_f32_32x32x16_bf16(pa1.v, ones, lacc, 0,0,0);
      __builtin_amdgcn_s_setprio(0);
    }
    asm volatile("s_waitcnt vmcnt(0)" ::: "memory");
    __syncthreads();
  }

  int b = bh >> 4, h = bh & 15;
  #pragma unroll
  for (int r=0;r<16;r++){
    int q = (r&3) + 8*(r>>2) + 4*hi;
    float inv = frcp(lacc[r]);
    size_t mrow = ((size_t)(b*SEQ + q0 + q))*DMODEL + (size_t)h*HDIM + l31;
    #pragma unroll
    for (int db=0; db<2; ++db)
      Ah[mrow + db*32] = f2bf(oa[db][r]*inv);
  }
}

// ---------------- output projection ----------------
__global__ __launch_bounds__(256) void gemm_out_k(
  const uint16_t* __restrict__ Ahp, const uint16_t* __restrict__ WoH, float* __restrict__ C)
{
  __shared__ uint16_t lA[128*32], lB[128*32];
  int m0 = blockIdx.x*128;
  int e0 = blockIdx.y*128;
  f32x4 acc[4][4];
  #pragma unroll
  for(int i=0;i<4;i++){
    #pragma unroll
    for(int j=0;j<4;j++) acc[i][j] = (f32x4){0.f,0.f,0.f,0.f};
  }
  gemm_mainloop(Ahp, WoH, m0, e0, lA, lB, acc);
  int t=threadIdx.x, lane=t&63, lq=lane&15, lg=lane>>4;
  int wr=t>>7, wc=(t>>6)&1;
  int rbase = m0 + wr*64 + lg*4;
  int cb = e0 + wc*64;
  #pragma unroll
  for(int mi=0;mi<4;mi++){
    #pragma unroll
    for(int ni=0;ni<4;ni++){
      #pragma unroll
      for(int r=0;r<4;r++)
        C[(size_t)(rbase+mi*16+r)*DMODEL + cb + ni*16 + lq] = acc[mi][ni][r];
    }
  }
}

extern "C" void kernel_launch(void* const* d_in, const int* in_sizes, int n_in,
                              void* d_out, int out_size, void* d_ws, size_t ws_size,
                              hipStream_t stream) {
  const float* x  = (const float*)d_in[0];
  const float* Wq = (const float*)d_in[1];
  const float* Wk = (const float*)d_in[2];
  const float* Wv = (const float*)d_in[3];
  const float* Wo = (const float*)d_in[4];
  float* out = (float*)d_out;
  char* ws = (char*)d_ws;

  float* sin_t = (float*)(ws + OFF_SIN);
  float* cos_t = (float*)(ws + OFF_COS);
  uint16_t* xhi = (uint16_t*)(ws + OFF_XHI);
  uint16_t* wqh = (uint16_t*)(ws + OFF_WQH);
  uint16_t* wkh = (uint16_t*)(ws + OFF_WKH);
  uint16_t* wvh = (uint16_t*)(ws + OFF_WVH);
  uint16_t* woh = (uint16_t*)(ws + OFF_WOH);
  uint16_t* Qr  = (uint16_t*)(ws + OFF_QR);
  uint16_t* Kr  = (uint16_t*)(ws + OFF_KR);
  uint16_t* Vt  = (uint16_t*)(ws + OFF_VT);
  uint16_t* ahi = (uint16_t*)(ws + OFF_AHI);

  rope_tables_k<<<dim3(256),dim3(256),0,stream>>>(sin_t, cos_t);
  cvt_k<<<dim3(8192),dim3(256),0,stream>>>(x, xhi, (MTOT*DMODEL)/4);
  cvtw_k<<<dim3(1024,4),dim3(256),0,stream>>>(Wq, Wk, Wv, Wo, wqh, wkh, wvh, woh);

  gemm_qkv_k<<<dim3(MTOT/256, 12),dim3(512),0,stream>>>(xhi, wqh, wkh, wvh,
                                                        sin_t, cos_t, Qr, Kr, Vt);
  attn_k<<<dim3(BATCH*NHEADS*(SEQ/128)),dim3(256),0,stream>>>(Qr, Kr, Vt, ahi);
  gemm_out_k<<<dim3(MTOT/128, 8),dim3(256),0,stream>>>(ahi, woh, out);
}

// Round 7
// 204.454 us; speedup vs baseline: 1.7403x; 1.1080x over previous
//
#include <hip/hip_runtime.h>
#include <stdint.h>

#define SEQ    2048
#define DMODEL 1024
#define NHEADS 16
#define HDIM   64
#define BATCH  4
#define MTOT   (BATCH*SEQ)

typedef __attribute__((ext_vector_type(8)))  short s16x8;
typedef __attribute__((ext_vector_type(4)))  short s16x4;
typedef __attribute__((ext_vector_type(4)))  float f32x4;
typedef __attribute__((ext_vector_type(16))) float f32x16;

// ---- workspace offsets (bytes) ----
#define OFF_SIN  ((size_t)0)          // 2048*32*4
#define OFF_COS  ((size_t)262144)
#define OFF_XHI  ((size_t)524288)     // 8192*1024*2
#define OFF_WQH  ((size_t)34078720)
#define OFF_WKH  ((size_t)38273024)
#define OFF_WVH  ((size_t)42467328)
#define OFF_WOH  ((size_t)46661632)
#define OFF_QR   ((size_t)50855936)   // [b,h,n,dh] bf16 (Q pre-scaled by 0.125*log2e)
#define OFF_KR   ((size_t)67633152)
#define OFF_VT   ((size_t)84410368)   // [b,h,dh,n] bf16 (transposed)
#define OFF_AHI  ((size_t)101187584)  // attn out [m,e] bf16

#define QSCALE 0.18033688011112042f

__device__ __forceinline__ uint16_t f2bf(float f){
  union{float f;uint32_t u;}v; v.f=f;
  uint32_t r=v.u+0x7fffu+((v.u>>16)&1u);
  return (uint16_t)(r>>16);
}
__device__ __forceinline__ float bf2f(uint16_t u){
  union{uint32_t u;float f;}v; v.u=((uint32_t)u)<<16; return v.f;
}

__device__ __forceinline__ void async16(void* lds, const void* g){
  __builtin_amdgcn_global_load_lds(
    (const __attribute__((address_space(1))) void*)g,
    (__attribute__((address_space(3))) void*)lds, 16, 0, 0);
}

__device__ __forceinline__ float fexp2(float x){
#if __has_builtin(__builtin_amdgcn_exp2f)
  return __builtin_amdgcn_exp2f(x);
#else
  float r; asm("v_exp_f32 %0, %1" : "=v"(r) : "v"(x)); return r;
#endif
}
__device__ __forceinline__ float frcp(float x){
#if __has_builtin(__builtin_amdgcn_rcpf)
  return __builtin_amdgcn_rcpf(x);
#else
  float r; asm("v_rcp_f32 %0, %1" : "=v"(r) : "v"(x)); return r;
#endif
}
// {o0,o1} = permlane32_swap(a,b)
__device__ __forceinline__ void plswap(unsigned a, unsigned b, unsigned &o0, unsigned &o1){
#if __has_builtin(__builtin_amdgcn_permlane32_swap)
  auto r = __builtin_amdgcn_permlane32_swap(a, b, false, false);
  o0 = (unsigned)r[0]; o1 = (unsigned)r[1];
#else
  unsigned ax = (unsigned)__shfl_xor((int)a, 32, 64);
  unsigned bx = (unsigned)__shfl_xor((int)b, 32, 64);
  bool hi = (threadIdx.x & 32) != 0;
  o0 = hi ? bx : a;
  o1 = hi ? b  : ax;
#endif
}

// ---------------- prep kernels ----------------
__global__ __launch_bounds__(256) void rope_tables_k(float* __restrict__ st, float* __restrict__ ct){
  int i = blockIdx.x*256 + threadIdx.x;
  if (i >= SEQ*32) return;
  int n = i>>5, j = i&31;
  double freq = pow(10000.0, -(double)j/32.0);
  double ang = (double)n*freq;
  st[i] = (float)sin(ang);
  ct[i] = (float)cos(ang);
}

__global__ __launch_bounds__(256) void cvt_k(const float* __restrict__ src,
                                             uint16_t* __restrict__ hi, int n4){
  int i = blockIdx.x*256 + threadIdx.x;
  if (i>=n4) return;
  f32x4 v = *(const f32x4*)(src + (size_t)i*4);
  s16x4 vh;
  #pragma unroll
  for(int r=0;r<4;r++) vh[r] = (short)f2bf(v[r]);
  *(s16x4*)(hi + (size_t)i*4) = vh;
}

__global__ __launch_bounds__(256) void cvtw_k(const float* __restrict__ s0, const float* __restrict__ s1,
                                              const float* __restrict__ s2, const float* __restrict__ s3,
                                              uint16_t* __restrict__ d0, uint16_t* __restrict__ d1,
                                              uint16_t* __restrict__ d2, uint16_t* __restrict__ d3){
  int i = blockIdx.x*256 + threadIdx.x;   // i < 262144
  int y = blockIdx.y;
  const float* s = y==0? s0 : y==1? s1 : y==2? s2 : s3;
  uint16_t*    d = y==0? d0 : y==1? d1 : y==2? d2 : d3;
  f32x4 v = *(const f32x4*)(s + (size_t)i*4);
  s16x4 vh;
  #pragma unroll
  for(int r=0;r<4;r++) vh[r] = (short)f2bf(v[r]);
  *(s16x4*)(d + (size_t)i*4) = vh;
}

// ---------------- GEMM core (128x128 tile, BK=64, XOR-swizzled LDS) ----------------
// LDS rows are 128B (64 bf16). Swizzle: 16B chunk c at row r stored at c^(r&7).
// Staged with linear global_load_lds dest + pre-swizzled global source (involution).
// Read (16-lane quarter, fixed lg): rows r..r+15, chunks (4kh+lg)^(r&7) -> 8 chunks x2 = conflict-free.
__device__ __forceinline__ void gemm_mainloop64(
  const uint16_t* __restrict__ A, const uint16_t* __restrict__ B,
  int m0, int e0, char* lA, char* lB, f32x4 acc[4][4])
{
  const int t = threadIdx.x;
  const int lane = t & 63;
  const int wr = t>>7, wc = (t>>6)&1;
  const int lq = lane&15, lg = lane>>4;
  const int rowA = wr*64 + lq;
  const int rowB = wc*64 + lq;

  // stage maps: dest byte d -> row d>>7, chunk (d>>4)&7; src chunk = dchunk ^ (row&7)
  int dbyte[4], srow[4], sbyte[4];
  #pragma unroll
  for (int s=0;s<4;s++){
    int d = s*4096 + t*16;
    int r = d>>7, c = (d>>4)&7;
    dbyte[s]=d; srow[s]=r; sbyte[s]=(c ^ (r&7))*16;
  }
  // read chunk byte-offsets per k-half
  int chh[2];
  #pragma unroll
  for (int kh=0;kh<2;kh++) chh[kh] = (((kh<<2)|lg) ^ (lq&7))*16;

  const char* Ab = (const char*)A;
  const char* Bb = (const char*)B;

  for (int k0=0; k0<DMODEL; k0+=64){
    #pragma unroll
    for (int s=0;s<4;s++){
      async16(lA + dbyte[s], Ab + (size_t)(m0+srow[s])*2048 + k0*2 + sbyte[s]);
      async16(lB + dbyte[s], Bb + (size_t)(e0+srow[s])*2048 + k0*2 + sbyte[s]);
    }
    __syncthreads();
    #pragma unroll
    for (int kh=0;kh<2;kh++){
      s16x8 af[4], bfr[4];
      #pragma unroll
      for (int mi=0;mi<4;mi++) af[mi]  = *(const s16x8*)(lA + (rowA+mi*16)*128 + chh[kh]);
      #pragma unroll
      for (int ni=0;ni<4;ni++) bfr[ni] = *(const s16x8*)(lB + (rowB+ni*16)*128 + chh[kh]);
      __builtin_amdgcn_s_setprio(1);
      #pragma unroll
      for (int mi=0;mi<4;mi++){
        #pragma unroll
        for (int ni=0;ni<4;ni++)
          acc[mi][ni] = __builtin_amdgcn_mfma_f32_16x16x32_bf16(af[mi], bfr[ni], acc[mi][ni],0,0,0);
      }
      __builtin_amdgcn_s_setprio(0);
    }
    __syncthreads();
  }
}

// ---------------- QKV projection + RoPE epilogue ----------------
__global__ __launch_bounds__(256) void gemm_qkv_k(
  const uint16_t* __restrict__ Xh,
  const uint16_t* __restrict__ WqH, const uint16_t* __restrict__ WkH, const uint16_t* __restrict__ WvH,
  const float* __restrict__ st, const float* __restrict__ ct,
  uint16_t* __restrict__ Qr, uint16_t* __restrict__ Kr, uint16_t* __restrict__ Vt)
{
  __shared__ char lA[128*128], lB[128*128];   // 16KB each
  int m0 = blockIdx.x*128;
  int cti = blockIdx.y;
  int seg = cti>>3;                 // 0=Q 1=K 2=V
  int e0 = (cti&7)*128;
  const uint16_t* W = seg==0? WqH : (seg==1? WkH : WvH);
  f32x4 acc[4][4];
  #pragma unroll
  for(int i=0;i<4;i++){
    #pragma unroll
    for(int j=0;j<4;j++) acc[i][j] = (f32x4){0.f,0.f,0.f,0.f};
  }
  gemm_mainloop64(Xh, W, m0, e0, lA, lB, acc);

  int t=threadIdx.x, lane=t&63, lq=lane&15, lg=lane>>4;
  int wr=t>>7, wc=(t>>6)&1;
  int eb = e0 + wc*64;
  int h = eb>>6;                    // wave col-span is head-aligned (64 wide)
  int rbase = m0 + wr*64 + lg*4;
  if (seg<2){
    uint16_t* O = seg==0? Qr:Kr;
    float qs = seg==0 ? QSCALE : 1.0f;  // 0.125*log2(e) folded into Q
    #pragma unroll
    for(int mi=0;mi<4;mi++){
      #pragma unroll
      for(int ni=0;ni<2;ni++){
        int j = ni*16+lq;           // 0..31, pairs with j+32 in frag ni+2
        #pragma unroll
        for(int r=0;r<4;r++){
          int m = rbase + mi*16 + r;
          int b = m>>11, n = m&2047;
          float sv = st[n*32+j], cv = ct[n*32+j];
          float x1 = acc[mi][ni][r], x2 = acc[mi][ni+2][r];
          size_t base = ((size_t)((b*NHEADS+h)*SEQ + n))*HDIM;
          O[base + j]      = f2bf((x1*cv - x2*sv)*qs);
          O[base + j + 32] = f2bf((x1*sv + x2*cv)*qs);
        }
      }
    }
  } else {
    #pragma unroll
    for(int mi=0;mi<4;mi++){
      #pragma unroll
      for(int ni=0;ni<4;ni++){
        int dh = ni*16+lq;
        int m = rbase + mi*16;
        int b = m>>11, n = m&2047;  // 4 consecutive n over regs
        s16x4 v;
        #pragma unroll
        for(int r=0;r<4;r++) v[r] = (short)f2bf(acc[mi][ni][r]);
        *(s16x4*)(Vt + ((size_t)((b*NHEADS+h)*HDIM + dh))*SEQ + n) = v;
      }
    }
  }
}

// ---------------- flash attention: fixed-max via MFMA C-init, T15 pipeline, depth-2 staging ----------------
__global__ __launch_bounds__(256) void attn_k(
  const uint16_t* __restrict__ Qr, const uint16_t* __restrict__ Kr, const uint16_t* __restrict__ Vt,
  uint16_t* __restrict__ Ah)
{
  __shared__ uint16_t ldsK[3][64*64];   // 3-deep: stage t+2 while computing t
  __shared__ uint16_t ldsV[3][64*64];

  int bid = blockIdx.x;
  int w = (bid & 7)*128 + (bid >> 3);   // XCD swizzle: 16 q-tiles of one bh per XCD
  int bh = w >> 4, qt = w & 15;
  int tid = threadIdx.x;
  int wid = tid >> 6, lane = tid & 63;
  int l31 = lane & 31, hi = lane >> 5;
  int q0 = qt*128 + wid*32;

  const uint16_t* Qb = Qr + (size_t)bh*SEQ*HDIM;
  const uint16_t* Kb = Kr + (size_t)bh*SEQ*HDIM;
  const uint16_t* Vb = Vt + (size_t)bh*HDIM*SEQ;

  // Q B-frags: col=q=l31, k=d=16*sp+8*hi+j  (Q pre-scaled by 0.125*log2e)
  s16x8 qf[4];
  #pragma unroll
  for (int sp=0; sp<4; ++sp)
    qf[sp] = *(const s16x8*)(Qb + (size_t)(q0 + l31)*HDIM + sp*16 + hi*8);

  s16x8 ones;
  #pragma unroll
  for (int j=0;j<8;j++) ones[j] = (short)0x3F80;

  // C-init trick: S - 16 computed for free by starting the MFMA chain at -16.
  f32x16 zm16;
  #pragma unroll
  for (int r=0;r<16;r++) zm16[r] = -16.0f;

  f32x16 oa[2], lacc;
  #pragma unroll
  for (int r=0;r<16;r++){ oa[0][r]=0.f; oa[1][r]=0.f; lacc[r]=0.f; }

  auto STAGE = [&](int buf, int t){
    const char* Ks = (const char*)(Kb + (size_t)t*64*HDIM);
    char* dK = (char*)&ldsK[buf][0];
    char* dV = (char*)&ldsV[buf][0];
    #pragma unroll
    for (int r=0; r<2; ++r){
      int ci = r*256 + tid;
      int sc = ci ^ ((ci>>3)&7);        // involution: pre-swizzled source, linear LDS dest
      async16(dK + ci*16, Ks + sc*16);
    }
    #pragma unroll
    for (int r=0; r<2; ++r){
      int ci = r*256 + tid;
      int row = ci>>3;
      int sc = (ci&7) ^ (row&7);
      async16(dV + ci*16, (const char*)Vb + ((size_t)row*SEQ + (size_t)t*64)*2 + sc*16);
    }
  };

  STAGE(0, 0);
  STAGE(1, 1);
  asm volatile("s_waitcnt vmcnt(4)" ::: "memory");   // tile0 ready, tile1 in flight
  __syncthreads();

  const int NT = SEQ/64;
  int cur = 0;
  for (int t=0; t<NT; ++t){
    int nxt2 = cur+2; if (nxt2>=3) nxt2-=3;
    if (t+2 < NT) STAGE(nxt2, t+2);
    const char* bK = (const char*)&ldsK[cur][0];
    const char* bV = (const char*)&ldsV[cur][0];

    // ---- QK for both subs up front (T15: MFMAs execute under softmax VALU) ----
    s16x8 kf0[4], kf1[4];
    #pragma unroll
    for (int sp=0; sp<4; ++sp){
      int cc = (2*sp + hi) ^ (l31 & 7);
      kf0[sp] = *(const s16x8*)(bK + l31*128 + cc*16);
      kf1[sp] = *(const s16x8*)(bK + (32+l31)*128 + cc*16);
    }
    f32x16 sacc0 = zm16, sacc1 = zm16;
    __builtin_amdgcn_s_setprio(1);
    #pragma unroll
    for (int sp=0; sp<4; ++sp)
      sacc0 = __builtin_amdgcn_mfma_f32_32x32x16_bf16(kf0[sp], qf[sp], sacc0, 0,0,0);
    #pragma unroll
    for (int sp=0; sp<4; ++sp)
      sacc1 = __builtin_amdgcn_mfma_f32_32x32x16_bf16(kf1[sp], qf[sp], sacc1, 0,0,0);
    __builtin_amdgcn_s_setprio(0);

    // prefetch V frags for sub0 (LDS latency under softmax0)
    s16x8 vf0[4];
    #pragma unroll
    for (int db=0; db<2; ++db)
      #pragma unroll
      for (int s=0; s<2; ++s){
        int cc = (2*s + hi) ^ (l31 & 7);
        vf0[db*2+s] = *(const s16x8*)(bV + (db*32+l31)*128 + cc*16);
      }

    // ---- softmax sub0 (S-16 already in sacc0) ----
    float p[16];
    #pragma unroll
    for (int r=0;r<16;r++) p[r] = fexp2(sacc0[r]);
    uint32_t pw[8];
    #pragma unroll
    for (int j=0;j<8;j++)
      asm("v_cvt_pk_bf16_f32 %0, %1, %2" : "=v"(pw[j]) : "v"(p[2*j]), "v"(p[2*j+1]));
    unsigned w0,w1,w2,w3, x0,x1,x2,x3;
    plswap(pw[0], pw[2], w0, w2);
    plswap(pw[1], pw[3], w1, w3);
    plswap(pw[4], pw[6], x0, x2);
    plswap(pw[5], pw[7], x1, x3);
    union { uint32_t wd[4]; s16x8 v; } pa0, pa1;
    pa0.wd[0]=w0; pa0.wd[1]=w1; pa0.wd[2]=w2; pa0.wd[3]=w3;
    pa1.wd[0]=x0; pa1.wd[1]=x1; pa1.wd[2]=x2; pa1.wd[3]=x3;
    __builtin_amdgcn_s_setprio(1);
    #pragma unroll
    for (int db=0; db<2; ++db){
      oa[db] = __builtin_amdgcn_mfma_f32_32x32x16_bf16(pa0.v, vf0[db*2+0], oa[db], 0,0,0);
      oa[db] = __builtin_amdgcn_mfma_f32_32x32x16_bf16(pa1.v, vf0[db*2+1], oa[db], 0,0,0);
    }
    lacc = __builtin_amdgcn_mfma_f32_32x32x16_bf16(pa0.v, ones, lacc, 0,0,0);
    lacc = __builtin_amdgcn_mfma_f32_32x32x16_bf16(pa1.v, ones, lacc, 0,0,0);
    __builtin_amdgcn_s_setprio(0);

    // prefetch V frags for sub1
    s16x8 vf1[4];
    #pragma unroll
    for (int db=0; db<2; ++db)
      #pragma unroll
      for (int s=0; s<2; ++s){
        int cc = (4 + 2*s + hi) ^ (l31 & 7);
        vf1[db*2+s] = *(const s16x8*)(bV + (db*32+l31)*128 + cc*16);
      }

    // ---- softmax sub1 (PV0 MFMAs execute under this) ----
    #pragma unroll
    for (int r=0;r<16;r++) p[r] = fexp2(sacc1[r]);
    #pragma unroll
    for (int j=0;j<8;j++)
      asm("v_cvt_pk_bf16_f32 %0, %1, %2" : "=v"(pw[j]) : "v"(p[2*j]), "v"(p[2*j+1]));
    plswap(pw[0], pw[2], w0, w2);
    plswap(pw[1], pw[3], w1, w3);
    plswap(pw[4], pw[6], x0, x2);
    plswap(pw[5], pw[7], x1, x3);
    pa0.wd[0]=w0; pa0.wd[1]=w1; pa0.wd[2]=w2; pa0.wd[3]=w3;
    pa1.wd[0]=x0; pa1.wd[1]=x1; pa1.wd[2]=x2; pa1.wd[3]=x3;
    __builtin_amdgcn_s_setprio(1);
    #pragma unroll
    for (int db=0; db<2; ++db){
      oa[db] = __builtin_amdgcn_mfma_f32_32x32x16_bf16(pa0.v, vf1[db*2+0], oa[db], 0,0,0);
      oa[db] = __builtin_amdgcn_mfma_f32_32x32x16_bf16(pa1.v, vf1[db*2+1], oa[db], 0,0,0);
    }
    lacc = __builtin_amdgcn_mfma_f32_32x32x16_bf16(pa0.v, ones, lacc, 0,0,0);
    lacc = __builtin_amdgcn_mfma_f32_32x32x16_bf16(pa1.v, ones, lacc, 0,0,0);
    __builtin_amdgcn_s_setprio(0);

    // counted wait: t+1's loads complete, t+2's (4) may stay in flight
    if (t+2 < NT)      asm volatile("s_waitcnt vmcnt(4)" ::: "memory");
    else if (t+1 < NT) asm volatile("s_waitcnt vmcnt(0)" ::: "memory");
    if (t+1 < NT)      asm volatile("s_barrier" ::: "memory");
    cur = cur+1; if (cur>=3) cur-=3;
  }

  // epilogue: L already in acc layout; normalize and write bf16
  int b = bh >> 4, h = bh & 15;
  #pragma unroll
  for (int r=0;r<16;r++){
    int q = (r&3) + 8*(r>>2) + 4*hi;
    float inv = frcp(lacc[r]);
    size_t mrow = ((size_t)(b*SEQ + q0 + q))*DMODEL + (size_t)h*HDIM + l31;
    #pragma unroll
    for (int db=0; db<2; ++db)
      Ah[mrow + db*32] = f2bf(oa[db][r]*inv);
  }
}

// ---------------- output projection ----------------
__global__ __launch_bounds__(256) void gemm_out_k(
  const uint16_t* __restrict__ Ahp, const uint16_t* __restrict__ WoH, float* __restrict__ C)
{
  __shared__ char lA[128*128], lB[128*128];
  int m0 = blockIdx.x*128;
  int e0 = blockIdx.y*128;
  f32x4 acc[4][4];
  #pragma unroll
  for(int i=0;i<4;i++){
    #pragma unroll
    for(int j=0;j<4;j++) acc[i][j] = (f32x4){0.f,0.f,0.f,0.f};
  }
  gemm_mainloop64(Ahp, WoH, m0, e0, lA, lB, acc);
  int t=threadIdx.x, lane=t&63, lq=lane&15, lg=lane>>4;
  int wr=t>>7, wc=(t>>6)&1;
  int rbase = m0 + wr*64 + lg*4;
  int cb = e0 + wc*64;
  #pragma unroll
  for(int mi=0;mi<4;mi++){
    #pragma unroll
    for(int ni=0;ni<4;ni++){
      #pragma unroll
      for(int r=0;r<4;r++)
        C[(size_t)(rbase+mi*16+r)*DMODEL + cb + ni*16 + lq] = acc[mi][ni][r];
    }
  }
}

extern "C" void kernel_launch(void* const* d_in, const int* in_sizes, int n_in,
                              void* d_out, int out_size, void* d_ws, size_t ws_size,
                              hipStream_t stream) {
  const float* x  = (const float*)d_in[0];
  const float* Wq = (const float*)d_in[1];
  const float* Wk = (const float*)d_in[2];
  const float* Wv = (const float*)d_in[3];
  const float* Wo = (const float*)d_in[4];
  float* out = (float*)d_out;
  char* ws = (char*)d_ws;

  float* sin_t = (float*)(ws + OFF_SIN);
  float* cos_t = (float*)(ws + OFF_COS);
  uint16_t* xhi = (uint16_t*)(ws + OFF_XHI);
  uint16_t* wqh = (uint16_t*)(ws + OFF_WQH);
  uint16_t* wkh = (uint16_t*)(ws + OFF_WKH);
  uint16_t* wvh = (uint16_t*)(ws + OFF_WVH);
  uint16_t* woh = (uint16_t*)(ws + OFF_WOH);
  uint16_t* Qr  = (uint16_t*)(ws + OFF_QR);
  uint16_t* Kr  = (uint16_t*)(ws + OFF_KR);
  uint16_t* Vt  = (uint16_t*)(ws + OFF_VT);
  uint16_t* ahi = (uint16_t*)(ws + OFF_AHI);

  rope_tables_k<<<dim3(256),dim3(256),0,stream>>>(sin_t, cos_t);
  cvt_k<<<dim3(8192),dim3(256),0,stream>>>(x, xhi, (MTOT*DMODEL)/4);
  cvtw_k<<<dim3(1024,4),dim3(256),0,stream>>>(Wq, Wk, Wv, Wo, wqh, wkh, wvh, woh);

  gemm_qkv_k<<<dim3(MTOT/128, 24),dim3(256),0,stream>>>(xhi, wqh, wkh, wvh,
                                                        sin_t, cos_t, Qr, Kr, Vt);
  attn_k<<<dim3(BATCH*NHEADS*(SEQ/128)),dim3(256),0,stream>>>(Qr, Kr, Vt, ahi);
  gemm_out_k<<<dim3(MTOT/128, 8),dim3(256),0,stream>>>(ahi, woh, out);
}